// Round 3
// baseline (4543.427 us; speedup 1.0000x reference)
//
#include <hip/hip_runtime.h>

#define NN 2048
#define BB 8
#define NITER 50
#define NBAND 64              // 32-row bands per batch
#define WPB 4                 // waves per block
#define RPW 8                 // rows per wave per band

// Work in the x*SCALE domain where SCALE = 100*log2(e), so exp(x*100) = exp2(x*SCALE)
// and eps*log_mu*SCALE = -log2(2048) = -11 exactly.
#define SCALE 144.269504088896f
#define INVSC 0.00693147180560f   // 1/SCALE = eps*ln2

__device__ __forceinline__ float max4(float a, float b, float c, float d) {
    return fmaxf(fmaxf(a, b), fmaxf(c, d));
}

// ---------------- init: zero v ----------------
__global__ __launch_bounds__(256) void k_init(float* __restrict__ v) {
    int idx = blockIdx.x * 256 + threadIdx.x;
    if (idx < BB * NN) v[idx] = 0.0f;
}

// ---------------- fused iteration: one pass over c ----------------
// Block = (batch b, 32-row band). Wave w owns 8 rows for the row-LSE (u update)
// and a fixed 512-column stripe for the column accumulation. Each round:
// row-LSE of one row per wave -> u_i, publish x=(c+u_i)*SCALE to lds_x, then all
// waves fold the 4 published rows into their stripe accumulators (4-row batched
// online LSE). Next row is prefetched into the other register buffer.
__global__ __launch_bounds__(256, 3) void k_iter(const float* __restrict__ c,
                                                 const float* __restrict__ v,
                                                 float* __restrict__ u,
                                                 float* __restrict__ pm,
                                                 float* __restrict__ ps) {
    __shared__ float lds_v[NN];           // v * SCALE
    __shared__ float lds_x[WPB][NN];      // (c + u_i) * SCALE, one row per wave

    int b    = blockIdx.x >> 6;
    int band = blockIdx.x & 63;
    int t    = threadIdx.x;
    int w    = t >> 6;
    int lane = t & 63;

    // stage v*SCALE into LDS
    const float4* vg = (const float4*)(v + b * NN);
    float4 va = vg[t], vb4 = vg[t + 256];
    ((float4*)lds_v)[t]       = make_float4(va.x * SCALE, va.y * SCALE, va.z * SCALE, va.w * SCALE);
    ((float4*)lds_v)[t + 256] = make_float4(vb4.x * SCALE, vb4.y * SCALE, vb4.z * SCALE, vb4.w * SCALE);
    __syncthreads();

    int row0 = band * (WPB * RPW) + w * RPW;
    const float* cb = c + ((size_t)b * NN + row0) * NN;

    // stripe accumulators: cols w*512 + k*256 + lane*4 + e, k in {0,1}
    float4 cm[2], cs[2];
    cm[0] = cm[1] = make_float4(-INFINITY, -INFINITY, -INFINITY, -INFINITY);
    cs[0] = cs[1] = make_float4(0.f, 0.f, 0.f, 0.f);

    float4 cr[2][8];
    {
        const float4* r0 = (const float4*)cb;
#pragma unroll
        for (int q = 0; q < 8; ++q) cr[0][q] = r0[q * 64 + lane];
    }

#pragma unroll
    for (int r = 0; r < RPW; ++r) {
        float4* A = cr[r & 1];
        // scale current row: A = c*SCALE
#pragma unroll
        for (int q = 0; q < 8; ++q) {
            A[q].x *= SCALE; A[q].y *= SCALE; A[q].z *= SCALE; A[q].w *= SCALE;
        }
        // prefetch next row (raw) into the other buffer
        if (r + 1 < RPW) {
            const float4* rn = (const float4*)(cb + (size_t)(r + 1) * NN);
            float4* Bf = cr[(r + 1) & 1];
#pragma unroll
            for (int q = 0; q < 8; ++q) Bf[q] = rn[q * 64 + lane];
        }

        // ---- row online LSE of (c+v)*SCALE ----
        float m = -INFINITY, s = 0.0f;
#pragma unroll
        for (int q = 0; q < 8; ++q) {
            float4 v2 = ((const float4*)lds_v)[q * 64 + lane];
            float x0 = A[q].x + v2.x;
            float x1 = A[q].y + v2.y;
            float x2 = A[q].z + v2.z;
            float x3 = A[q].w + v2.w;
            float lm = max4(x0, x1, x2, x3);
            float M  = fmaxf(m, lm);
            s = s * exp2f(m - M)
              + exp2f(x0 - M) + exp2f(x1 - M) + exp2f(x2 - M) + exp2f(x3 - M);
            m = M;
        }
        // wave butterfly reduce (all lanes converge)
#pragma unroll
        for (int off = 32; off; off >>= 1) {
            float om = __shfl_xor(m, off, 64);
            float os = __shfl_xor(s, off, 64);
            float M = fmaxf(m, om);
            s = s * exp2f(m - M) + os * exp2f(om - M);
            m = M;
        }
        float u2 = -11.0f - m - __log2f(s);       // u * SCALE
        if (lane == 0) u[b * NN + row0 + r] = u2 * INVSC;

        __syncthreads();   // previous round's lds_x readers are done
        // publish x = (c + u_i) * SCALE
        {
            float4* xw = (float4*)lds_x[w];
#pragma unroll
            for (int q = 0; q < 8; ++q) {
                float4 o;
                o.x = A[q].x + u2; o.y = A[q].y + u2;
                o.z = A[q].z + u2; o.w = A[q].w + u2;
                xw[q * 64 + lane] = o;
            }
        }
        __syncthreads();   // all 4 rows visible

        // ---- fold 4 published rows into stripe accumulators ----
#pragma unroll
        for (int k = 0; k < 2; ++k) {
            int o4 = w * 128 + k * 64 + lane;     // float4 index into a 2048-row
            float4 x0 = ((const float4*)lds_x[0])[o4];
            float4 x1 = ((const float4*)lds_x[1])[o4];
            float4 x2 = ((const float4*)lds_x[2])[o4];
            float4 x3 = ((const float4*)lds_x[3])[o4];
#pragma unroll
            for (int e = 0; e < 4; ++e) {
                float y0 = (&x0.x)[e], y1 = (&x1.x)[e], y2 = (&x2.x)[e], y3 = (&x3.x)[e];
                float& m_ = (&cm[k].x)[e];
                float& s_ = (&cs[k].x)[e];
                float lm = max4(y0, y1, y2, y3);
                float M  = fmaxf(m_, lm);
                s_ = s_ * exp2f(m_ - M)
                   + exp2f(y0 - M) + exp2f(y1 - M) + exp2f(y2 - M) + exp2f(y3 - M);
                m_ = M;
            }
        }
    }

    // write stripe partials (SCALE domain)
    size_t obase = (size_t)(b * NBAND + band) * NN;
#pragma unroll
    for (int k = 0; k < 2; ++k) {
        int o4 = w * 128 + k * 64 + lane;
        ((float4*)(pm + obase))[o4] = cm[k];
        ((float4*)(ps + obase))[o4] = cs[k];
    }
}

// ---------------- combine band partials -> v ----------------
__global__ __launch_bounds__(256) void k_v_combine(const float* __restrict__ pm,
                                                   const float* __restrict__ ps,
                                                   float* __restrict__ v) {
    int idx = blockIdx.x * 256 + threadIdx.x;   // b*NN + j
    int b = idx >> 11;
    int j = idx & (NN - 1);
    float m = -INFINITY, s = 0.0f;
    for (int r = 0; r < NBAND; ++r) {
        size_t o = (size_t)(b * NBAND + r) * NN + j;
        float om = pm[o], os = ps[o];
        float M = fmaxf(m, om);
        s = s * exp2f(m - M) + os * exp2f(om - M);
        m = M;
    }
    float val = (-11.0f - m - __log2f(s)) * INVSC;
    if (val > 9e8f) val = 0.0f;   // reference's huge-value clamp (never fires)
    v[idx] = val;
}

// ---------------- finalize: pi = exp2((c+u+v)*SCALE), negc = -c ----------------
__global__ __launch_bounds__(256) void k_final(const float* __restrict__ c,
                                               const float* __restrict__ u,
                                               const float* __restrict__ v,
                                               float* __restrict__ pi,
                                               float* __restrict__ negc) {
    unsigned q = blockIdx.x * 256 + threadIdx.x;     // float4 index
    unsigned e = q * 4;
    unsigned b = e >> 22;
    unsigned rem = e & (NN * NN - 1);
    unsigned i = rem >> 11;
    unsigned j = rem & (NN - 1);

    float4 cc = ((const float4*)c)[q];
    float ui = u[b * NN + i];
    float4 vv = *(const float4*)(v + b * NN + j);

    float4 p;
    p.x = exp2f((cc.x + ui + vv.x) * SCALE);
    p.y = exp2f((cc.y + ui + vv.y) * SCALE);
    p.z = exp2f((cc.z + ui + vv.z) * SCALE);
    p.w = exp2f((cc.w + ui + vv.w) * SCALE);
    ((float4*)pi)[q] = p;

    float4 nc = { -cc.x, -cc.y, -cc.z, -cc.w };
    ((float4*)negc)[q] = nc;
}

// ---------------- copy u, v to output ----------------
__global__ __launch_bounds__(256) void k_uv_out(const float* __restrict__ u,
                                                const float* __restrict__ v,
                                                float* __restrict__ ou,
                                                float* __restrict__ ov) {
    int idx = blockIdx.x * 256 + threadIdx.x;
    if (idx < BB * NN) { ou[idx] = u[idx]; ov[idx] = v[idx]; }
}

extern "C" void kernel_launch(void* const* d_in, const int* in_sizes, int n_in,
                              void* d_out, int out_size, void* d_ws, size_t ws_size,
                              hipStream_t stream) {
    const float* c = (const float*)d_in[0];
    float* out  = (float*)d_out;
    float* pi   = out;
    float* negc = out + (size_t)BB * NN * NN;
    float* ou   = out + 2 * (size_t)BB * NN * NN;
    float* ov   = ou + BB * NN;

    float* ws = (float*)d_ws;
    float* u  = ws;                          // BB*NN
    float* v  = ws + BB * NN;                // BB*NN
    float* pm = ws + 2 * BB * NN;            // BB*NBAND*NN
    float* ps = pm + (size_t)BB * NBAND * NN;

    k_init<<<(BB * NN) / 256, 256, 0, stream>>>(v);

    for (int it = 0; it < NITER; ++it) {
        k_iter<<<BB * NBAND, 256, 0, stream>>>(c, v, u, pm, ps);
        k_v_combine<<<(BB * NN) / 256, 256, 0, stream>>>(pm, ps, v);
    }

    unsigned n4 = (unsigned)((size_t)BB * NN * NN / 4);
    k_final<<<n4 / 256, 256, 0, stream>>>(c, u, v, pi, negc);
    k_uv_out<<<(BB * NN) / 256, 256, 0, stream>>>(u, v, ou, ov);
}